// Round 1
// baseline (1444.414 us; speedup 1.0000x reference)
//
#include <hip/hip_runtime.h>

#define BB 4096
#define TT 64
#define NI 60
#define NH 60
#define NC 600
#define KF 7680   // T * 2H
#define NG 180    // 3H

__device__ __forceinline__ float sigf(float v)      { return 1.f / (1.f + __expf(-v)); }
__device__ __forceinline__ float tanhfast(float v)  { return 2.f / (1.f + __expf(-2.f * v)) - 1.f; }

// Fused GRU: per block = 32 batch rows x 1 direction. Wave layout: 4 rows x 16
// unit-groups; unit-group u owns hidden units j = u + 16k (u<12: 4 units, else 3).
// Both matvecs (w_ih . x_t and w_hh . h) computed from LDS-staged weights.
// h broadcast via double-buffered LDS, 1 barrier/step.
__global__ __launch_bounds__(512, 2) void gru_kernel(
    const float* __restrict__ x,      // [B][T][NI]
    const float* __restrict__ w_ih,   // [2][NG][NI]
    const float* __restrict__ w_hh,   // [2][NG][NH]
    const float* __restrict__ b_ih,   // [2][NG]
    const float* __restrict__ b_hh,   // [2][NG]
    float* __restrict__ hsT)          // [KF][B]  (k = t*120 + d*60 + j)
{
    __shared__ float Wih[NG * NI];        // 43.2 KB
    __shared__ float Whh[NG * NH];        // 43.2 KB
    __shared__ float hbuf[2][32][NH];     // 15.4 KB

    const int tid = threadIdx.x;
    const int d  = blockIdx.y;
    const int b0 = blockIdx.x * 32;

    // stage weights (row-major [g][i], 16B-aligned rows: 60*4=240B)
    {
        const float4* srcI = (const float4*)(w_ih + (size_t)d * NG * NI);
        const float4* srcH = (const float4*)(w_hh + (size_t)d * NG * NH);
        float4* dstI = (float4*)Wih;
        float4* dstH = (float4*)Whh;
        for (int f = tid; f < (NG * NI) / 4; f += 512) { dstI[f] = srcI[f]; dstH[f] = srcH[f]; }
    }

    const int wave = tid >> 6;
    const int lane = tid & 63;
    const int r    = (wave << 2) + (lane >> 4);   // row within block [0,32)
    const int u    = lane & 15;                   // unit group
    const int brow = b0 + r;

    // biases for my units (j = u+16k): [gate][k]
    float bir[4], biz[4], bin_[4], bhr[4], bhz[4], bhn[4];
#pragma unroll
    for (int k = 0; k < 4; ++k) {
        const int j = u + 16 * k;
        if (j < NH) {
            bir[k]  = b_ih[d * NG + j];
            biz[k]  = b_ih[d * NG + 60 + j];
            bin_[k] = b_ih[d * NG + 120 + j];
            bhr[k]  = b_hh[d * NG + j];
            bhz[k]  = b_hh[d * NG + 60 + j];
            bhn[k]  = b_hh[d * NG + 120 + j];
        } else {
            bir[k] = biz[k] = bin_[k] = bhr[k] = bhz[k] = bhn[k] = 0.f;
        }
    }

    float hr[NH];                 // full h, constant-indexed only
#pragma unroll
    for (int i = 0; i < NH; ++i) hr[i] = 0.f;
    float hown[4] = {0.f, 0.f, 0.f, 0.f};   // my units' h (avoids runtime reg-array index)

    __syncthreads();

    for (int s = 0; s < TT; ++s) {
        const int tt = d ? (TT - 1 - s) : s;

        // ---- pass 1: hidden-side dots (uses hr; hr dead afterwards) ----
        float chr[4], chz[4], chn[4];
#pragma unroll
        for (int k = 0; k < 4; ++k) {
            const int j = u + 16 * k;
            chr[k] = chz[k] = chn[k] = 0.f;
            if (j < NH) {
                const float4* r0 = (const float4*)&Whh[(j) * NH];
                const float4* r1 = (const float4*)&Whh[(60 + j) * NH];
                const float4* r2 = (const float4*)&Whh[(120 + j) * NH];
#pragma unroll
                for (int q = 0; q < 15; ++q) {
                    const float4 a = r0[q], b = r1[q], c = r2[q];
                    chr[k] += a.x * hr[4*q] + a.y * hr[4*q+1] + a.z * hr[4*q+2] + a.w * hr[4*q+3];
                    chz[k] += b.x * hr[4*q] + b.y * hr[4*q+1] + b.z * hr[4*q+2] + b.w * hr[4*q+3];
                    chn[k] += c.x * hr[4*q] + c.y * hr[4*q+1] + c.z * hr[4*q+2] + c.w * hr[4*q+3];
                }
            }
        }

        // ---- pass 2: input-side dots (xr born here) ----
        float xr[NI];
        {
            const float4* xp = (const float4*)(x + ((size_t)brow * TT + tt) * NI);
#pragma unroll
            for (int q = 0; q < 15; ++q) {
                const float4 v = xp[q];
                xr[4*q] = v.x; xr[4*q+1] = v.y; xr[4*q+2] = v.z; xr[4*q+3] = v.w;
            }
        }
        float hnew[4];
#pragma unroll
        for (int k = 0; k < 4; ++k) {
            const int j = u + 16 * k;
            hnew[k] = 0.f;
            if (j < NH) {
                const float4* r0 = (const float4*)&Wih[(j) * NI];
                const float4* r1 = (const float4*)&Wih[(60 + j) * NI];
                const float4* r2 = (const float4*)&Wih[(120 + j) * NI];
                float ar = 0.f, az = 0.f, an = 0.f;
#pragma unroll
                for (int q = 0; q < 15; ++q) {
                    const float4 a = r0[q], b = r1[q], c = r2[q];
                    ar += a.x * xr[4*q] + a.y * xr[4*q+1] + a.z * xr[4*q+2] + a.w * xr[4*q+3];
                    az += b.x * xr[4*q] + b.y * xr[4*q+1] + b.z * xr[4*q+2] + b.w * xr[4*q+3];
                    an += c.x * xr[4*q] + c.y * xr[4*q+1] + c.z * xr[4*q+2] + c.w * xr[4*q+3];
                }
                const float rr = sigf(ar + bir[k] + chr[k] + bhr[k]);
                const float zz = sigf(az + biz[k] + chz[k] + bhz[k]);
                const float nn = tanhfast(an + bin_[k] + rr * (chn[k] + bhn[k]));
                hnew[k] = (1.f - zz) * nn + zz * hown[k];
                hown[k] = hnew[k];
            }
        }

        // ---- publish h, broadcast, store ----
        const int buf = s & 1;
#pragma unroll
        for (int k = 0; k < 4; ++k) {
            const int j = u + 16 * k;
            if (j < NH) hbuf[buf][r][j] = hnew[k];
        }
        __syncthreads();

        {
            const float4* hp = (const float4*)&hbuf[buf][r][0];
#pragma unroll
            for (int q = 0; q < 15; ++q) {
                const float4 v = hp[q];
                hr[4*q] = v.x; hr[4*q+1] = v.y; hr[4*q+2] = v.z; hr[4*q+3] = v.w;
            }
        }
        // cooperative coalesced store of this step's 32x60 h tile to hsT
        const size_t kbase = (size_t)tt * 120 + (size_t)d * 60;
        for (int idx = tid; idx < 32 * NH; idx += 512) {
            const int j2 = idx >> 5, rb = idx & 31;
            hsT[(kbase + j2) * BB + b0 + rb] = hbuf[buf][rb][j2];
        }
    }
}

// FC: out[b][c] = sum_k hsT[k][b] * fcw[c][k] + fcb[c]
// 64x64 tile, BK=32, 256 threads, thread tile 4x4.
__global__ __launch_bounds__(256) void fc_kernel(
    const float* __restrict__ hsT,   // [KF][B]
    const float* __restrict__ fcw,   // [NC][KF]
    const float* __restrict__ fcb,   // [NC]
    float* __restrict__ out)         // [B][NC]
{
    __shared__ float As[32][64];     // [k][b]
    __shared__ float Ws[32][68];     // [k][c], padded

    const int tid = threadIdx.x;
    const int tx = tid & 15;         // c
    const int ty = tid >> 4;         // b
    const int b0 = blockIdx.x * 64;
    const int c0 = blockIdx.y * 64;

    float acc[4][4] = {};

    for (int k0 = 0; k0 < KF; k0 += 32) {
#pragma unroll
        for (int h = 0; h < 2; ++h) {
            const int f = tid + h * 256;
            const int ki = f >> 4, b4 = f & 15;
            *(float4*)&As[ki][b4 * 4] =
                *(const float4*)&hsT[(size_t)(k0 + ki) * BB + b0 + b4 * 4];
        }
#pragma unroll
        for (int h = 0; h < 2; ++h) {
            const int f = tid + h * 256;
            const int ci = f >> 3, k4 = f & 7;
            float4 v = make_float4(0.f, 0.f, 0.f, 0.f);
            if (c0 + ci < NC)
                v = *(const float4*)&fcw[(size_t)(c0 + ci) * KF + k0 + k4 * 4];
            Ws[k4 * 4 + 0][ci] = v.x;
            Ws[k4 * 4 + 1][ci] = v.y;
            Ws[k4 * 4 + 2][ci] = v.z;
            Ws[k4 * 4 + 3][ci] = v.w;
        }
        __syncthreads();
#pragma unroll
        for (int k = 0; k < 32; ++k) {
            const float4 a = *(const float4*)&As[k][ty * 4];
            const float4 w = *(const float4*)&Ws[k][tx * 4];
            acc[0][0] += a.x * w.x; acc[0][1] += a.x * w.y; acc[0][2] += a.x * w.z; acc[0][3] += a.x * w.w;
            acc[1][0] += a.y * w.x; acc[1][1] += a.y * w.y; acc[1][2] += a.y * w.z; acc[1][3] += a.y * w.w;
            acc[2][0] += a.z * w.x; acc[2][1] += a.z * w.y; acc[2][2] += a.z * w.z; acc[2][3] += a.z * w.w;
            acc[3][0] += a.w * w.x; acc[3][1] += a.w * w.y; acc[3][2] += a.w * w.z; acc[3][3] += a.w * w.w;
        }
        __syncthreads();
    }

    const int c = c0 + tx * 4;
    if (c + 3 < NC) {
        const float4 bias = *(const float4*)&fcb[c];
#pragma unroll
        for (int bi = 0; bi < 4; ++bi) {
            const float4 v = make_float4(acc[bi][0] + bias.x, acc[bi][1] + bias.y,
                                         acc[bi][2] + bias.z, acc[bi][3] + bias.w);
            *(float4*)&out[(size_t)(b0 + ty * 4 + bi) * NC + c] = v;
        }
    }
}

extern "C" void kernel_launch(void* const* d_in, const int* in_sizes, int n_in,
                              void* d_out, int out_size, void* d_ws, size_t ws_size,
                              hipStream_t stream) {
    (void)in_sizes; (void)n_in; (void)out_size;
    const float* x    = (const float*)d_in[0];
    const float* w_ih = (const float*)d_in[1];
    const float* w_hh = (const float*)d_in[2];
    const float* b_ih = (const float*)d_in[3];
    const float* b_hh = (const float*)d_in[4];
    const float* fcw  = (const float*)d_in[5];
    const float* fcb  = (const float*)d_in[6];
    float* out = (float*)d_out;
    float* hsT = (float*)d_ws;                       // [KF][B] fp32 = 125.8 MB

    if (ws_size < (size_t)KF * BB * sizeof(float)) return;  // scratch too small -> visible failure

    gru_kernel<<<dim3(BB / 32, 2), 512, 0, stream>>>(x, w_ih, w_hh, b_ih, b_hh, hsT);
    fc_kernel<<<dim3(BB / 64, (NC + 63) / 64), 256, 0, stream>>>(hsT, fcw, fcb, out);
}